// Round 5
// baseline (242.165 us; speedup 1.0000x reference)
//
#include <hip/hip_runtime.h>

#define BATCH        16384
#define SEQ          500
#define NUM_BUCKETS  4000000
#define NUM_FIELDS   63
#define NUM_SEGMENTS 64

typedef int         int4v   __attribute__((ext_vector_type(4)));
typedef float       float4v __attribute__((ext_vector_type(4)));
typedef signed char schar;
typedef schar       char4v  __attribute__((ext_vector_type(4)));

#define N_VEC4     (NUM_BUCKETS / 4)        // 1,000,000 float4 groups
#define SLICE_LOG2 12                       // 4096 floats per quant slice
#define N_SLICES   ((NUM_BUCKETS + 4095) >> SLICE_LOG2)   // 977
#define SCALES_OFF NUM_BUCKETS              // byte offset of scales[] in d_ws

// main kernel: 256 threads = 4 waves, 2 rows/wave -> 8 rows per block.
// launch_bounds(256,8) allows full 32-wave/CU occupancy (R4's (512,4) capped
// it at ~50%); LDS 5.9 KB/block permits 8 blocks/CU.
#define BLOCK_MAIN    256
#define ROWS_PER_WAVE 2
#define ROWS_PER_BLK  8

#define BLOCK_Q 256

// ---- k1: ONE-pass per-slice quantization (verified: the 4 MB int8 table IS
// L2-resident -- round-3 fp32 A/B showed FETCH 80->433 MB and 2x time without it).
__global__ __launch_bounds__(BLOCK_Q) void quant_slice(
    const float4v* __restrict__ src, char4v* __restrict__ dst,
    float* __restrict__ scales)
{
    __shared__ float red[BLOCK_Q / 64];
    const int t     = threadIdx.x;
    const int base4 = blockIdx.x << (SLICE_LOG2 - 2);

    float4v v[4];
    float m = 0.0f;
    #pragma unroll
    for (int k = 0; k < 4; ++k) {
        const int i4 = base4 + k * BLOCK_Q + t;
        if (i4 < N_VEC4) {
            v[k] = src[i4];
            #pragma unroll
            for (int j = 0; j < 4; ++j) m = fmaxf(m, fabsf(v[k][j]));
        } else {
            v[k] = (float4v){0.f, 0.f, 0.f, 0.f};
        }
    }
    #pragma unroll
    for (int off = 32; off >= 1; off >>= 1)
        m = fmaxf(m, __shfl_down(m, off, 64));
    if ((t & 63) == 0) red[t >> 6] = m;
    __syncthreads();
    const float bm  = fmaxf(fmaxf(red[0], red[1]), fmaxf(red[2], red[3]));
    const float inv = (bm > 0.f) ? 127.0f / bm : 0.0f;
    if (t == 0) scales[blockIdx.x] = bm * (1.0f / 127.0f);

    #pragma unroll
    for (int k = 0; k < 4; ++k) {
        const int i4 = base4 + k * BLOCK_Q + t;
        if (i4 < N_VEC4) {
            char4v q;
            #pragma unroll
            for (int j = 0; j < 4; ++j) {
                float r = fminf(fmaxf(v[k][j] * inv, -127.f), 127.f);
                q[j] = (schar)(int)rintf(r);
            }
            dst[i4] = q;
        }
    }
}

// ---- k2: main. int8 L2-resident gather + LDS segment-sum.
// Gather pipe is MSHR/latency bound (0.22 gathers/cyc/CU vs >=1 for every
// other sub-pipe). This round: (a) NT-mark the table gathers -- random 1B
// reads get zero L1 reuse, so skip L1 line allocation and its miss-tracking
// entry; (b) restore full occupancy (256thr blocks, launch_bounds(256,8)).
__global__ __launch_bounds__(BLOCK_MAIN, 8) void wide_pool_i8(
    const int*   __restrict__ indexes,
    const int*   __restrict__ fields,
    const float* __restrict__ values,
    const schar* __restrict__ table8,
    const float* __restrict__ scales,
    float*       __restrict__ out)
{
    __shared__ float acc[ROWS_PER_BLK][NUM_SEGMENTS];
    __shared__ float sscale[N_SLICES];

    const int tid  = threadIdx.x;
    const int wave = tid >> 6;
    const int lane = tid & 63;

    acc[2 * wave][lane]     = 0.0f;
    acc[2 * wave + 1][lane] = 0.0f;
    for (int i = tid; i < N_SLICES; i += BLOCK_MAIN)
        sscale[i] = scales[i];
    __syncthreads();

    const long r0 = (long)blockIdx.x * ROWS_PER_BLK + 2 * wave;
    const long r1 = r0 + 1;

    const int4v*   i0 = (const int4v*)  (indexes + r0 * SEQ);
    const int4v*   f0 = (const int4v*)  (fields  + r0 * SEQ);
    const float4v* v0 = (const float4v*)(values  + r0 * SEQ);
    const int4v*   i1 = (const int4v*)  (indexes + r1 * SEQ);
    const int4v*   f1 = (const int4v*)  (fields  + r1 * SEQ);
    const float4v* v1 = (const float4v*)(values  + r1 * SEQ);

    const bool second = (lane < 125 - 64);   // 500 = 125 vec4 per row

    // stage 1: ALL streaming loads for both rows issued up front
    // (non-temporal: zero reuse -> don't evict the table from L2)
    int4v   ia0 = __builtin_nontemporal_load(&i0[lane]);
    int4v   ia1 = __builtin_nontemporal_load(&i1[lane]);
    int4v   fa0 = __builtin_nontemporal_load(&f0[lane]);
    int4v   fa1 = __builtin_nontemporal_load(&f1[lane]);
    float4v va0 = __builtin_nontemporal_load(&v0[lane]);
    float4v va1 = __builtin_nontemporal_load(&v1[lane]);
    int4v   ib0 = {0,0,0,0}, ib1 = {0,0,0,0};
    int4v   fb0 = {0,0,0,0}, fb1 = {0,0,0,0};
    float4v vb0 = {0.f,0.f,0.f,0.f}, vb1 = {0.f,0.f,0.f,0.f};
    if (second) {
        ib0 = __builtin_nontemporal_load(&i0[lane + 64]);
        ib1 = __builtin_nontemporal_load(&i1[lane + 64]);
        fb0 = __builtin_nontemporal_load(&f0[lane + 64]);
        fb1 = __builtin_nontemporal_load(&f1[lane + 64]);
        vb0 = __builtin_nontemporal_load(&v0[lane + 64]);
        vb1 = __builtin_nontemporal_load(&v1[lane + 64]);
    }

    // stage 2: 16 independent int8 gathers in flight, NT (no L1 allocation)
    // (bucket 0 quantizes to exactly 0 -> no padding guard)
    int   b[16];
    float q[16];
    #pragma unroll
    for (int j = 0; j < 4; ++j) { b[j]      = ia0[j] % NUM_BUCKETS; }
    #pragma unroll
    for (int j = 0; j < 4; ++j) { b[4 + j]  = ia1[j] % NUM_BUCKETS; }
    #pragma unroll
    for (int j = 0; j < 4; ++j) { b[8 + j]  = second ? (ib0[j] % NUM_BUCKETS) : 0; }
    #pragma unroll
    for (int j = 0; j < 4; ++j) { b[12 + j] = second ? (ib1[j] % NUM_BUCKETS) : 0; }
    #pragma unroll
    for (int j = 0; j < 16; ++j)
        q[j] = (float)__builtin_nontemporal_load(&table8[b[j]]);

    // stage 3: LDS segment-sum with per-slice dequant from LDS
    #pragma unroll
    for (int j = 0; j < 4; ++j) {
        atomicAdd(&acc[2 * wave][fa0[j] & (NUM_SEGMENTS - 1)],
                  q[j] * sscale[b[j] >> SLICE_LOG2] * va0[j]);
        atomicAdd(&acc[2 * wave + 1][fa1[j] & (NUM_SEGMENTS - 1)],
                  q[4 + j] * sscale[b[4 + j] >> SLICE_LOG2] * va1[j]);
    }
    if (second) {
        #pragma unroll
        for (int j = 0; j < 4; ++j) {
            atomicAdd(&acc[2 * wave][fb0[j] & (NUM_SEGMENTS - 1)],
                      q[8 + j] * sscale[b[8 + j] >> SLICE_LOG2] * vb0[j]);
            atomicAdd(&acc[2 * wave + 1][fb1[j] & (NUM_SEGMENTS - 1)],
                      q[12 + j] * sscale[b[12 + j] >> SLICE_LOG2] * vb1[j]);
        }
    }

    __syncthreads();

    if (lane >= 1) {
        __builtin_nontemporal_store(acc[2 * wave][lane],
                                    &out[r0 * NUM_FIELDS + (lane - 1)]);
        __builtin_nontemporal_store(acc[2 * wave + 1][lane],
                                    &out[r1 * NUM_FIELDS + (lane - 1)]);
    }
}

// ---- fallback: direct fp32 gather (only if d_ws too small for the table)
#define BLOCK_F 256
#define ROWS_F  4
__global__ __launch_bounds__(BLOCK_F, 8) void wide_pool_f32(
    const int*   __restrict__ indexes,
    const int*   __restrict__ fields,
    const float* __restrict__ values,
    const float* __restrict__ table,
    float*       __restrict__ out)
{
    __shared__ float acc[ROWS_F][NUM_SEGMENTS];
    const int tid  = threadIdx.x;
    const int wave = tid >> 6;
    const int lane = tid & 63;
    acc[wave][lane] = 0.0f;
    __syncthreads();
    const long row  = (long)blockIdx.x * ROWS_F + wave;
    const long base = row * SEQ;
    const int4v*   idx4 = (const int4v*)  (indexes + base);
    const int4v*   fld4 = (const int4v*)  (fields  + base);
    const float4v* val4 = (const float4v*)(values  + base);
    const bool second = (lane < 125 - 64);
    int4v   ia = __builtin_nontemporal_load(&idx4[lane]);
    int4v   fa = __builtin_nontemporal_load(&fld4[lane]);
    float4v va = __builtin_nontemporal_load(&val4[lane]);
    int4v   ib = {0,0,0,0}; int4v fb = {0,0,0,0}; float4v vb = {0.f,0.f,0.f,0.f};
    if (second) {
        ib = __builtin_nontemporal_load(&idx4[lane + 64]);
        fb = __builtin_nontemporal_load(&fld4[lane + 64]);
        vb = __builtin_nontemporal_load(&val4[lane + 64]);
    }
    float e[8];
    #pragma unroll
    for (int j = 0; j < 4; ++j) e[j] = table[ia[j] % NUM_BUCKETS];
    #pragma unroll
    for (int j = 0; j < 4; ++j) e[4 + j] = second ? table[ib[j] % NUM_BUCKETS] : 0.0f;
    #pragma unroll
    for (int j = 0; j < 4; ++j)
        atomicAdd(&acc[wave][fa[j] & (NUM_SEGMENTS - 1)], e[j] * va[j]);
    if (second) {
        #pragma unroll
        for (int j = 0; j < 4; ++j)
            atomicAdd(&acc[wave][fb[j] & (NUM_SEGMENTS - 1)], e[4 + j] * vb[j]);
    }
    __syncthreads();
    if (lane >= 1) out[row * NUM_FIELDS + (lane - 1)] = acc[wave][lane];
}

extern "C" void kernel_launch(void* const* d_in, const int* in_sizes, int n_in,
                              void* d_out, int out_size, void* d_ws, size_t ws_size,
                              hipStream_t stream) {
    const int*   indexes = (const int*)  d_in[0];
    const int*   fields  = (const int*)  d_in[1];
    const float* values  = (const float*)d_in[2];
    const float* table   = (const float*)d_in[3];
    float*       out     = (float*)      d_out;

    const size_t need = (size_t)NUM_BUCKETS + 4 * (size_t)N_SLICES;  // 4 MB + 3.9 KB
    if (ws_size >= need) {
        schar* t8  = (schar*)d_ws;
        float* scl = (float*)((char*)d_ws + SCALES_OFF);
        quant_slice<<<N_SLICES, BLOCK_Q, 0, stream>>>(
            (const float4v*)table, (char4v*)t8, scl);
        wide_pool_i8<<<BATCH / ROWS_PER_BLK, BLOCK_MAIN, 0, stream>>>(
            indexes, fields, values, t8, scl, out);
    } else {
        wide_pool_f32<<<BATCH / ROWS_F, BLOCK_F, 0, stream>>>(
            indexes, fields, values, table, out);
    }
}

// Round 6
// 179.708 us; speedup vs baseline: 1.3475x; 1.3475x over previous
//
#include <hip/hip_runtime.h>

#define BATCH        16384
#define SEQ          500
#define NUM_BUCKETS  4000000
#define NUM_FIELDS   63
#define NUM_SEGMENTS 64

typedef int         int4v   __attribute__((ext_vector_type(4)));
typedef float       float4v __attribute__((ext_vector_type(4)));
typedef signed char schar;
typedef schar       char4v  __attribute__((ext_vector_type(4)));

#define N_VEC4     (NUM_BUCKETS / 4)        // 1,000,000 float4 groups
#define SLICE_LOG2 12                       // 4096 floats per quant slice
#define N_SLICES   ((NUM_BUCKETS + 4095) >> SLICE_LOG2)   // 977
#define SCALES_OFF NUM_BUCKETS              // byte offset of scales[] in d_ws

// main kernel: 256 threads = 4 waves, 2 rows/wave -> 8 rows per block.
// (256,8): full occupancy headroom; R4's (512,4) capped at 50%.
#define BLOCK_MAIN    256
#define ROWS_PER_WAVE 2
#define ROWS_PER_BLK  8

#define BLOCK_Q 256

// ---- k1: ONE-pass per-slice quantization.
// VERIFIED (R3 fp32 A/B + R5 nt A/B): the 4 MB int8 table must stay
// L2-resident; without it FETCH explodes 80->350+ MB and time doubles.
__global__ __launch_bounds__(BLOCK_Q) void quant_slice(
    const float4v* __restrict__ src, char4v* __restrict__ dst,
    float* __restrict__ scales)
{
    __shared__ float red[BLOCK_Q / 64];
    const int t     = threadIdx.x;
    const int base4 = blockIdx.x << (SLICE_LOG2 - 2);

    float4v v[4];
    float m = 0.0f;
    #pragma unroll
    for (int k = 0; k < 4; ++k) {
        const int i4 = base4 + k * BLOCK_Q + t;
        if (i4 < N_VEC4) {
            v[k] = src[i4];
            #pragma unroll
            for (int j = 0; j < 4; ++j) m = fmaxf(m, fabsf(v[k][j]));
        } else {
            v[k] = (float4v){0.f, 0.f, 0.f, 0.f};
        }
    }
    #pragma unroll
    for (int off = 32; off >= 1; off >>= 1)
        m = fmaxf(m, __shfl_down(m, off, 64));
    if ((t & 63) == 0) red[t >> 6] = m;
    __syncthreads();
    const float bm  = fmaxf(fmaxf(red[0], red[1]), fmaxf(red[2], red[3]));
    const float inv = (bm > 0.f) ? 127.0f / bm : 0.0f;
    if (t == 0) scales[blockIdx.x] = bm * (1.0f / 127.0f);

    #pragma unroll
    for (int k = 0; k < 4; ++k) {
        const int i4 = base4 + k * BLOCK_Q + t;
        if (i4 < N_VEC4) {
            char4v q;
            #pragma unroll
            for (int j = 0; j < 4; ++j) {
                float r = fminf(fmaxf(v[k][j] * inv, -127.f), 127.f);
                q[j] = (schar)(int)rintf(r);
            }
            dst[i4] = q;
        }
    }
}

// ---- k2: main. int8 L2-resident gather + LDS segment-sum.
// Table gathers are PLAIN loads (R5: nt = evict-first, killed L2 residency).
// Gather pipe is MSHR/latency bound at ~0.22 lane-gathers/cyc/CU; this round
// isolates the occupancy knob (50% -> target >=62%) that R4 gave away.
__global__ __launch_bounds__(BLOCK_MAIN, 8) void wide_pool_i8(
    const int*   __restrict__ indexes,
    const int*   __restrict__ fields,
    const float* __restrict__ values,
    const schar* __restrict__ table8,
    const float* __restrict__ scales,
    float*       __restrict__ out)
{
    __shared__ float acc[ROWS_PER_BLK][NUM_SEGMENTS];
    __shared__ float sscale[N_SLICES];

    const int tid  = threadIdx.x;
    const int wave = tid >> 6;
    const int lane = tid & 63;

    acc[2 * wave][lane]     = 0.0f;
    acc[2 * wave + 1][lane] = 0.0f;
    for (int i = tid; i < N_SLICES; i += BLOCK_MAIN)
        sscale[i] = scales[i];
    __syncthreads();

    const long r0 = (long)blockIdx.x * ROWS_PER_BLK + 2 * wave;
    const long r1 = r0 + 1;

    const int4v*   i0 = (const int4v*)  (indexes + r0 * SEQ);
    const int4v*   f0 = (const int4v*)  (fields  + r0 * SEQ);
    const float4v* v0 = (const float4v*)(values  + r0 * SEQ);
    const int4v*   i1 = (const int4v*)  (indexes + r1 * SEQ);
    const int4v*   f1 = (const int4v*)  (fields  + r1 * SEQ);
    const float4v* v1 = (const float4v*)(values  + r1 * SEQ);

    const bool second = (lane < 125 - 64);   // 500 = 125 vec4 per row

    // stage 1: ALL streaming loads for both rows issued up front
    // (non-temporal is correct HERE: zero reuse, keep L2 for the table)
    int4v   ia0 = __builtin_nontemporal_load(&i0[lane]);
    int4v   ia1 = __builtin_nontemporal_load(&i1[lane]);
    int4v   fa0 = __builtin_nontemporal_load(&f0[lane]);
    int4v   fa1 = __builtin_nontemporal_load(&f1[lane]);
    float4v va0 = __builtin_nontemporal_load(&v0[lane]);
    float4v va1 = __builtin_nontemporal_load(&v1[lane]);
    int4v   ib0 = {0,0,0,0}, ib1 = {0,0,0,0};
    int4v   fb0 = {0,0,0,0}, fb1 = {0,0,0,0};
    float4v vb0 = {0.f,0.f,0.f,0.f}, vb1 = {0.f,0.f,0.f,0.f};
    if (second) {
        ib0 = __builtin_nontemporal_load(&i0[lane + 64]);
        ib1 = __builtin_nontemporal_load(&i1[lane + 64]);
        fb0 = __builtin_nontemporal_load(&f0[lane + 64]);
        fb1 = __builtin_nontemporal_load(&f1[lane + 64]);
        vb0 = __builtin_nontemporal_load(&v0[lane + 64]);
        vb1 = __builtin_nontemporal_load(&v1[lane + 64]);
    }

    // stage 2: 16 independent int8 gathers in flight, PLAIN loads (L2-hits)
    // (bucket 0 quantizes to exactly 0 -> no padding guard)
    int   b[16];
    float q[16];
    #pragma unroll
    for (int j = 0; j < 4; ++j) { b[j]      = ia0[j] % NUM_BUCKETS; }
    #pragma unroll
    for (int j = 0; j < 4; ++j) { b[4 + j]  = ia1[j] % NUM_BUCKETS; }
    #pragma unroll
    for (int j = 0; j < 4; ++j) { b[8 + j]  = second ? (ib0[j] % NUM_BUCKETS) : 0; }
    #pragma unroll
    for (int j = 0; j < 4; ++j) { b[12 + j] = second ? (ib1[j] % NUM_BUCKETS) : 0; }
    #pragma unroll
    for (int j = 0; j < 16; ++j) q[j] = (float)table8[b[j]];

    // stage 3: LDS segment-sum with per-slice dequant from LDS
    #pragma unroll
    for (int j = 0; j < 4; ++j) {
        atomicAdd(&acc[2 * wave][fa0[j] & (NUM_SEGMENTS - 1)],
                  q[j] * sscale[b[j] >> SLICE_LOG2] * va0[j]);
        atomicAdd(&acc[2 * wave + 1][fa1[j] & (NUM_SEGMENTS - 1)],
                  q[4 + j] * sscale[b[4 + j] >> SLICE_LOG2] * va1[j]);
    }
    if (second) {
        #pragma unroll
        for (int j = 0; j < 4; ++j) {
            atomicAdd(&acc[2 * wave][fb0[j] & (NUM_SEGMENTS - 1)],
                      q[8 + j] * sscale[b[8 + j] >> SLICE_LOG2] * vb0[j]);
            atomicAdd(&acc[2 * wave + 1][fb1[j] & (NUM_SEGMENTS - 1)],
                      q[12 + j] * sscale[b[12 + j] >> SLICE_LOG2] * vb1[j]);
        }
    }

    __syncthreads();

    if (lane >= 1) {
        __builtin_nontemporal_store(acc[2 * wave][lane],
                                    &out[r0 * NUM_FIELDS + (lane - 1)]);
        __builtin_nontemporal_store(acc[2 * wave + 1][lane],
                                    &out[r1 * NUM_FIELDS + (lane - 1)]);
    }
}

// ---- fallback: direct fp32 gather (only if d_ws too small for the table)
#define BLOCK_F 256
#define ROWS_F  4
__global__ __launch_bounds__(BLOCK_F, 8) void wide_pool_f32(
    const int*   __restrict__ indexes,
    const int*   __restrict__ fields,
    const float* __restrict__ values,
    const float* __restrict__ table,
    float*       __restrict__ out)
{
    __shared__ float acc[ROWS_F][NUM_SEGMENTS];
    const int tid  = threadIdx.x;
    const int wave = tid >> 6;
    const int lane = tid & 63;
    acc[wave][lane] = 0.0f;
    __syncthreads();
    const long row  = (long)blockIdx.x * ROWS_F + wave;
    const long base = row * SEQ;
    const int4v*   idx4 = (const int4v*)  (indexes + base);
    const int4v*   fld4 = (const int4v*)  (fields  + base);
    const float4v* val4 = (const float4v*)(values  + base);
    const bool second = (lane < 125 - 64);
    int4v   ia = __builtin_nontemporal_load(&idx4[lane]);
    int4v   fa = __builtin_nontemporal_load(&fld4[lane]);
    float4v va = __builtin_nontemporal_load(&val4[lane]);
    int4v   ib = {0,0,0,0}; int4v fb = {0,0,0,0}; float4v vb = {0.f,0.f,0.f,0.f};
    if (second) {
        ib = __builtin_nontemporal_load(&idx4[lane + 64]);
        fb = __builtin_nontemporal_load(&fld4[lane + 64]);
        vb = __builtin_nontemporal_load(&val4[lane + 64]);
    }
    float e[8];
    #pragma unroll
    for (int j = 0; j < 4; ++j) e[j] = table[ia[j] % NUM_BUCKETS];
    #pragma unroll
    for (int j = 0; j < 4; ++j) e[4 + j] = second ? table[ib[j] % NUM_BUCKETS] : 0.0f;
    #pragma unroll
    for (int j = 0; j < 4; ++j)
        atomicAdd(&acc[wave][fa[j] & (NUM_SEGMENTS - 1)], e[j] * va[j]);
    if (second) {
        #pragma unroll
        for (int j = 0; j < 4; ++j)
            atomicAdd(&acc[wave][fb[j] & (NUM_SEGMENTS - 1)], e[4 + j] * vb[j]);
    }
    __syncthreads();
    if (lane >= 1) out[row * NUM_FIELDS + (lane - 1)] = acc[wave][lane];
}

extern "C" void kernel_launch(void* const* d_in, const int* in_sizes, int n_in,
                              void* d_out, int out_size, void* d_ws, size_t ws_size,
                              hipStream_t stream) {
    const int*   indexes = (const int*)  d_in[0];
    const int*   fields  = (const int*)  d_in[1];
    const float* values  = (const float*)d_in[2];
    const float* table   = (const float*)d_in[3];
    float*       out     = (float*)      d_out;

    const size_t need = (size_t)NUM_BUCKETS + 4 * (size_t)N_SLICES;  // 4 MB + 3.9 KB
    if (ws_size >= need) {
        schar* t8  = (schar*)d_ws;
        float* scl = (float*)((char*)d_ws + SCALES_OFF);
        quant_slice<<<N_SLICES, BLOCK_Q, 0, stream>>>(
            (const float4v*)table, (char4v*)t8, scl);
        wide_pool_i8<<<BATCH / ROWS_PER_BLK, BLOCK_MAIN, 0, stream>>>(
            indexes, fields, values, t8, scl, out);
    } else {
        wide_pool_f32<<<BATCH / ROWS_F, BLOCK_F, 0, stream>>>(
            indexes, fields, values, table, out);
    }
}

// Round 7
// 172.385 us; speedup vs baseline: 1.4048x; 1.0425x over previous
//
#include <hip/hip_runtime.h>

#define BATCH        16384
#define SEQ          500
#define NUM_BUCKETS  4000000
#define NUM_FIELDS   63
#define NUM_SEGMENTS 64

typedef int         int4v   __attribute__((ext_vector_type(4)));
typedef float       float4v __attribute__((ext_vector_type(4)));
typedef signed char schar;
typedef schar       char4v  __attribute__((ext_vector_type(4)));

#define N_VEC4     (NUM_BUCKETS / 4)        // 1,000,000 float4 groups
#define SLICE_LOG2 12                       // 4096 floats per quant slice
#define N_SLICES   ((NUM_BUCKETS + 4095) >> SLICE_LOG2)   // 977
#define SCALES_OFF NUM_BUCKETS              // byte offset of scales[] in d_ws

// main kernel: EXACT round-4 optimum. 512 threads = 8 waves, 2 rows/wave,
// launch_bounds(512,4) -> ~50% occupancy. Measured across the session:
//   50% occ / 16 gathers/thread : 61.5 us   <- best (this config)
//   66% occ /  8 gathers/thread : 64.8 us
//   62% occ / 16 gathers/thread : 67.4 us   (256-thread blocks, R6)
// The gather pipe is per-CU line-fill-capacity bound (~0.22 gathers/cyc/CU
// = ~64 MSHRs / ~220cy L2 latency); occupancy beyond ~16 waves/CU only adds
// queueing + per-block staging overhead.
#define BLOCK_MAIN    512
#define ROWS_PER_WAVE 2
#define ROWS_PER_BLK  16

#define BLOCK_Q 256

// ---- k1: ONE-pass per-slice quantization.
// VERIFIED (R3 fp32 A/B + R5 nt A/B): the 4 MB int8 table must stay
// L2-resident; without it FETCH explodes 80->350+ MB and time doubles.
__global__ __launch_bounds__(BLOCK_Q) void quant_slice(
    const float4v* __restrict__ src, char4v* __restrict__ dst,
    float* __restrict__ scales)
{
    __shared__ float red[BLOCK_Q / 64];
    const int t     = threadIdx.x;
    const int base4 = blockIdx.x << (SLICE_LOG2 - 2);

    float4v v[4];
    float m = 0.0f;
    #pragma unroll
    for (int k = 0; k < 4; ++k) {
        const int i4 = base4 + k * BLOCK_Q + t;
        if (i4 < N_VEC4) {
            v[k] = src[i4];
            #pragma unroll
            for (int j = 0; j < 4; ++j) m = fmaxf(m, fabsf(v[k][j]));
        } else {
            v[k] = (float4v){0.f, 0.f, 0.f, 0.f};
        }
    }
    #pragma unroll
    for (int off = 32; off >= 1; off >>= 1)
        m = fmaxf(m, __shfl_down(m, off, 64));
    if ((t & 63) == 0) red[t >> 6] = m;
    __syncthreads();
    const float bm  = fmaxf(fmaxf(red[0], red[1]), fmaxf(red[2], red[3]));
    const float inv = (bm > 0.f) ? 127.0f / bm : 0.0f;
    if (t == 0) scales[blockIdx.x] = bm * (1.0f / 127.0f);

    #pragma unroll
    for (int k = 0; k < 4; ++k) {
        const int i4 = base4 + k * BLOCK_Q + t;
        if (i4 < N_VEC4) {
            char4v q;
            #pragma unroll
            for (int j = 0; j < 4; ++j) {
                float r = fminf(fmaxf(v[k][j] * inv, -127.f), 127.f);
                q[j] = (schar)(int)rintf(r);
            }
            dst[i4] = q;
        }
    }
}

// ---- k2: main. int8 L2-resident gather + LDS segment-sum.
// Table gathers are PLAIN loads (R5: nt = evict-first, kills L2 residency).
__global__ __launch_bounds__(BLOCK_MAIN, 4) void wide_pool_i8(
    const int*   __restrict__ indexes,
    const int*   __restrict__ fields,
    const float* __restrict__ values,
    const schar* __restrict__ table8,
    const float* __restrict__ scales,
    float*       __restrict__ out)
{
    __shared__ float acc[ROWS_PER_BLK][NUM_SEGMENTS];
    __shared__ float sscale[N_SLICES];

    const int tid  = threadIdx.x;
    const int wave = tid >> 6;
    const int lane = tid & 63;

    acc[2 * wave][lane]     = 0.0f;
    acc[2 * wave + 1][lane] = 0.0f;
    for (int i = tid; i < N_SLICES; i += BLOCK_MAIN)
        sscale[i] = scales[i];
    __syncthreads();

    const long r0 = (long)blockIdx.x * ROWS_PER_BLK + 2 * wave;
    const long r1 = r0 + 1;

    const int4v*   i0 = (const int4v*)  (indexes + r0 * SEQ);
    const int4v*   f0 = (const int4v*)  (fields  + r0 * SEQ);
    const float4v* v0 = (const float4v*)(values  + r0 * SEQ);
    const int4v*   i1 = (const int4v*)  (indexes + r1 * SEQ);
    const int4v*   f1 = (const int4v*)  (fields  + r1 * SEQ);
    const float4v* v1 = (const float4v*)(values  + r1 * SEQ);

    const bool second = (lane < 125 - 64);   // 500 = 125 vec4 per row

    // stage 1: ALL streaming loads for both rows issued up front
    // (non-temporal is correct HERE: zero reuse, keep L2 for the table)
    int4v   ia0 = __builtin_nontemporal_load(&i0[lane]);
    int4v   ia1 = __builtin_nontemporal_load(&i1[lane]);
    int4v   fa0 = __builtin_nontemporal_load(&f0[lane]);
    int4v   fa1 = __builtin_nontemporal_load(&f1[lane]);
    float4v va0 = __builtin_nontemporal_load(&v0[lane]);
    float4v va1 = __builtin_nontemporal_load(&v1[lane]);
    int4v   ib0 = {0,0,0,0}, ib1 = {0,0,0,0};
    int4v   fb0 = {0,0,0,0}, fb1 = {0,0,0,0};
    float4v vb0 = {0.f,0.f,0.f,0.f}, vb1 = {0.f,0.f,0.f,0.f};
    if (second) {
        ib0 = __builtin_nontemporal_load(&i0[lane + 64]);
        ib1 = __builtin_nontemporal_load(&i1[lane + 64]);
        fb0 = __builtin_nontemporal_load(&f0[lane + 64]);
        fb1 = __builtin_nontemporal_load(&f1[lane + 64]);
        vb0 = __builtin_nontemporal_load(&v0[lane + 64]);
        vb1 = __builtin_nontemporal_load(&v1[lane + 64]);
    }

    // stage 2: 16 independent int8 gathers in flight, PLAIN loads (L2-hits)
    // (bucket 0 quantizes to exactly 0 -> no padding guard)
    int   b[16];
    float q[16];
    #pragma unroll
    for (int j = 0; j < 4; ++j) { b[j]      = ia0[j] % NUM_BUCKETS; }
    #pragma unroll
    for (int j = 0; j < 4; ++j) { b[4 + j]  = ia1[j] % NUM_BUCKETS; }
    #pragma unroll
    for (int j = 0; j < 4; ++j) { b[8 + j]  = second ? (ib0[j] % NUM_BUCKETS) : 0; }
    #pragma unroll
    for (int j = 0; j < 4; ++j) { b[12 + j] = second ? (ib1[j] % NUM_BUCKETS) : 0; }
    #pragma unroll
    for (int j = 0; j < 16; ++j) q[j] = (float)table8[b[j]];

    // stage 3: LDS segment-sum with per-slice dequant from LDS
    #pragma unroll
    for (int j = 0; j < 4; ++j) {
        atomicAdd(&acc[2 * wave][fa0[j] & (NUM_SEGMENTS - 1)],
                  q[j] * sscale[b[j] >> SLICE_LOG2] * va0[j]);
        atomicAdd(&acc[2 * wave + 1][fa1[j] & (NUM_SEGMENTS - 1)],
                  q[4 + j] * sscale[b[4 + j] >> SLICE_LOG2] * va1[j]);
    }
    if (second) {
        #pragma unroll
        for (int j = 0; j < 4; ++j) {
            atomicAdd(&acc[2 * wave][fb0[j] & (NUM_SEGMENTS - 1)],
                      q[8 + j] * sscale[b[8 + j] >> SLICE_LOG2] * vb0[j]);
            atomicAdd(&acc[2 * wave + 1][fb1[j] & (NUM_SEGMENTS - 1)],
                      q[12 + j] * sscale[b[12 + j] >> SLICE_LOG2] * vb1[j]);
        }
    }

    __syncthreads();

    if (lane >= 1) {
        __builtin_nontemporal_store(acc[2 * wave][lane],
                                    &out[r0 * NUM_FIELDS + (lane - 1)]);
        __builtin_nontemporal_store(acc[2 * wave + 1][lane],
                                    &out[r1 * NUM_FIELDS + (lane - 1)]);
    }
}

// ---- fallback: direct fp32 gather (only if d_ws too small for the table)
#define BLOCK_F 256
#define ROWS_F  4
__global__ __launch_bounds__(BLOCK_F, 8) void wide_pool_f32(
    const int*   __restrict__ indexes,
    const int*   __restrict__ fields,
    const float* __restrict__ values,
    const float* __restrict__ table,
    float*       __restrict__ out)
{
    __shared__ float acc[ROWS_F][NUM_SEGMENTS];
    const int tid  = threadIdx.x;
    const int wave = tid >> 6;
    const int lane = tid & 63;
    acc[wave][lane] = 0.0f;
    __syncthreads();
    const long row  = (long)blockIdx.x * ROWS_F + wave;
    const long base = row * SEQ;
    const int4v*   idx4 = (const int4v*)  (indexes + base);
    const int4v*   fld4 = (const int4v*)  (fields  + base);
    const float4v* val4 = (const float4v*)(values  + base);
    const bool second = (lane < 125 - 64);
    int4v   ia = __builtin_nontemporal_load(&idx4[lane]);
    int4v   fa = __builtin_nontemporal_load(&fld4[lane]);
    float4v va = __builtin_nontemporal_load(&val4[lane]);
    int4v   ib = {0,0,0,0}; int4v fb = {0,0,0,0}; float4v vb = {0.f,0.f,0.f,0.f};
    if (second) {
        ib = __builtin_nontemporal_load(&idx4[lane + 64]);
        fb = __builtin_nontemporal_load(&fld4[lane + 64]);
        vb = __builtin_nontemporal_load(&val4[lane + 64]);
    }
    float e[8];
    #pragma unroll
    for (int j = 0; j < 4; ++j) e[j] = table[ia[j] % NUM_BUCKETS];
    #pragma unroll
    for (int j = 0; j < 4; ++j) e[4 + j] = second ? table[ib[j] % NUM_BUCKETS] : 0.0f;
    #pragma unroll
    for (int j = 0; j < 4; ++j)
        atomicAdd(&acc[wave][fa[j] & (NUM_SEGMENTS - 1)], e[j] * va[j]);
    if (second) {
        #pragma unroll
        for (int j = 0; j < 4; ++j)
            atomicAdd(&acc[wave][fb[j] & (NUM_SEGMENTS - 1)], e[4 + j] * vb[j]);
    }
    __syncthreads();
    if (lane >= 1) out[row * NUM_FIELDS + (lane - 1)] = acc[wave][lane];
}

extern "C" void kernel_launch(void* const* d_in, const int* in_sizes, int n_in,
                              void* d_out, int out_size, void* d_ws, size_t ws_size,
                              hipStream_t stream) {
    const int*   indexes = (const int*)  d_in[0];
    const int*   fields  = (const int*)  d_in[1];
    const float* values  = (const float*)d_in[2];
    const float* table   = (const float*)d_in[3];
    float*       out     = (float*)      d_out;

    const size_t need = (size_t)NUM_BUCKETS + 4 * (size_t)N_SLICES;  // 4 MB + 3.9 KB
    if (ws_size >= need) {
        schar* t8  = (schar*)d_ws;
        float* scl = (float*)((char*)d_ws + SCALES_OFF);
        quant_slice<<<N_SLICES, BLOCK_Q, 0, stream>>>(
            (const float4v*)table, (char4v*)t8, scl);
        wide_pool_i8<<<BATCH / ROWS_PER_BLK, BLOCK_MAIN, 0, stream>>>(
            indexes, fields, values, t8, scl, out);
    } else {
        wide_pool_f32<<<BATCH / ROWS_F, BLOCK_F, 0, stream>>>(
            indexes, fields, values, table, out);
    }
}